// Round 1
// baseline (94.361 us; speedup 1.0000x reference)
//
#include <hip/hip_runtime.h>
#include <math.h>

// Chamfer loss, B=32, N=2048, 3 used components.
// R3 restructure: one block per (batch, 128-row chunk); block loops over all
// 8 q-chunks of 256 (double-buffered LDS, register prefetch, 1 barrier/chunk).
// Row minima finish in-block -> fused sqrt+sum, NO atomicMin, NO ws sentinel.
// Col partial minima (over the block's 128 rows, per wave = 32 rows) stored
// non-atomically to private ws slots; kernel2 reduces 64 slots/col, adds |q|^2,
// sqrt, sums, and folds the 512 per-block row-sums. 3 dispatches total.
// Per-pair math identical to R2: q' = {-2x,-2y,-2z,|q|^2}, p = {x,y,z,|p|^2}
//   dot' = p.q'(xyz); row min(dot'+y2); col min(dot'+x2); 6 VALU/pair.

#define NPTS   2048
#define NBATCH 32
#define ROWCH  128
#define NBI    (NPTS / ROWCH)          // 16 row-chunks per batch
#define NQCH   (NPTS / 256)            // 8 q-chunks
#define COLPART_FLOATS ((size_t)NBATCH * NBI * 4 * NPTS)   // 16 MiB col partials
#define EPSF   1e-16f
#define BIGF   3.4e38f

__device__ __forceinline__ float min3f(float a, float b, float c) {
    return fminf(fminf(a, b), c);      // -> v_min3_f32
}

__global__ __launch_bounds__(256) void chamfer_main_kernel(
    const float* __restrict__ P, const float* __restrict__ Q,
    float* __restrict__ ws)
{
    __shared__ float4 sq[2][256];      // {-2x,-2y,-2z,|q|^2}, double-buffered
    __shared__ float  rsum[4];

    const int tid  = threadIdx.x;
    const int tx   = tid & 15;         // col group
    const int ty   = tid >> 4;         // row group 0..15
    const int lane = tid & 63;
    const int wv   = tid >> 6;
    const int bi   = blockIdx.x;       // row chunk 0..15
    const int b    = blockIdx.y;       // batch

    // ---- p rows r = ty + 16k (k<8) in registers; 4 distinct lines/wave -> L1
    const float4* Pb = (const float4*)P + (size_t)b * NPTS + (size_t)bi * ROWCH;
    float px[8], py[8], pz[8], x2[8], rowacc[8];
    #pragma unroll
    for (int k = 0; k < 8; ++k) {
        float4 v = Pb[ty + 16 * k];
        px[k] = v.y; py[k] = v.z; pz[k] = v.w;
        x2[k] = v.y * v.y + v.z * v.z + v.w * v.w;
        rowacc[k] = BIGF;
    }

    const float4* Qb = (const float4*)Q + (size_t)b * NPTS;
    {   // stage q-chunk 0
        float4 qv = Qb[tid];
        sq[0][tid] = make_float4(-2.f * qv.y, -2.f * qv.z, -2.f * qv.w,
                                 qv.y * qv.y + qv.z * qv.z + qv.w * qv.w);
    }
    __syncthreads();

    // private col-partial row for this (b, bi, wave)
    float* colbase = ws + (((size_t)b * NBI + bi) * 4 + wv) * NPTS;

    for (int jc = 0; jc < NQCH; ++jc) {
        const int cur = jc & 1;
        const bool have = (jc + 1 < NQCH);
        float4 qnext;
        if (have) qnext = Qb[(jc + 1) * 256 + tid];   // prefetch early (reg)

        float colv[16];
        #pragma unroll
        for (int jp = 0; jp < 8; ++jp) {
            float4 q0 = sq[cur][tx + 32 * jp];
            float4 q1 = sq[cur][tx + 32 * jp + 16];
            float c0 = BIGF, c1 = BIGF;
            #pragma unroll
            for (int k = 0; k < 8; k += 2) {
                float t00 = fmaf(px[k],   q0.x, fmaf(py[k],   q0.y, pz[k]   * q0.z));
                float t01 = fmaf(px[k],   q1.x, fmaf(py[k],   q1.y, pz[k]   * q1.z));
                float t10 = fmaf(px[k+1], q0.x, fmaf(py[k+1], q0.y, pz[k+1] * q0.z));
                float t11 = fmaf(px[k+1], q1.x, fmaf(py[k+1], q1.y, pz[k+1] * q1.z));
                rowacc[k]   = min3f(rowacc[k],   t00 + q0.w, t01 + q1.w);
                rowacc[k+1] = min3f(rowacc[k+1], t10 + q0.w, t11 + q1.w);
                c0 = min3f(c0, t00 + x2[k], t10 + x2[k+1]);
                c1 = min3f(c1, t01 + x2[k], t11 + x2[k+1]);
            }
            colv[2*jp]     = c0;
            colv[2*jp + 1] = c1;
        }

        // col reduce over ty within wave (lane bits 4,5) -> all lanes hold min
        #pragma unroll
        for (int j = 0; j < 16; ++j) {
            float v = colv[j];
            v = fminf(v, __shfl_xor(v, 16));
            v = fminf(v, __shfl_xor(v, 32));
            colv[j] = v;
        }
        if (lane < 16) {               // lane == tx representative, static j index
            #pragma unroll
            for (int j = 0; j < 16; ++j)
                colbase[jc * 256 + j * 16 + lane] = colv[j];
        }

        if (have) {                    // write-late half of the staging split
            sq[cur ^ 1][tid] = make_float4(
                -2.f * qnext.y, -2.f * qnext.z, -2.f * qnext.w,
                qnext.y * qnext.y + qnext.z * qnext.z + qnext.w * qnext.w);
        }
        __syncthreads();
    }

    // ---- row epilogue: reduce over tx (lane bits 0..3), fused sqrt+sum
    float rs = 0.f;
    #pragma unroll
    for (int k = 0; k < 8; ++k) {
        float v = rowacc[k];
        v = fminf(v, __shfl_xor(v, 1));
        v = fminf(v, __shfl_xor(v, 2));
        v = fminf(v, __shfl_xor(v, 4));
        v = fminf(v, __shfl_xor(v, 8));
        rs += sqrtf(fmaxf(x2[k] + v, 0.f) + EPSF);
    }
    if (tx != 0) rs = 0.f;             // 16x duplicate across tx
    rs += __shfl_xor(rs, 16);
    rs += __shfl_xor(rs, 32);
    if (lane == 0) rsum[wv] = rs;
    __syncthreads();
    if (tid == 0)
        ws[COLPART_FLOATS + (size_t)b * NBI + bi] =
            (rsum[0] + rsum[1]) + (rsum[2] + rsum[3]);
}

__global__ __launch_bounds__(256) void chamfer_finish_kernel(
    const float* __restrict__ ws, const float* __restrict__ Q,
    float* __restrict__ out)
{
    __shared__ float rbuf[4];
    const int tid = threadIdx.x;
    const int b   = blockIdx.x >> 3;
    const int cc  = blockIdx.x & 7;
    const int col = cc * 256 + tid;

    // min over 16 bi x 4 waves private partials (coalesced, stride NPTS)
    const float* base = ws + (size_t)b * NBI * 4 * NPTS + col;
    float v = BIGF;
    #pragma unroll
    for (int i = 0; i < NBI * 4; ++i)
        v = fminf(v, base[(size_t)i * NPTS]);

    float4 qv = ((const float4*)Q)[(size_t)b * NPTS + col];
    float y2 = qv.y * qv.y + qv.z * qv.z + qv.w * qv.w;
    float s = sqrtf(fmaxf(v + y2, 0.f) + EPSF);

    // fold the 512 per-block row-sum partials (2 per finish-block)
    if (tid < 2) s += ws[COLPART_FLOATS + (size_t)blockIdx.x * 2 + tid];

    #pragma unroll
    for (int off = 32; off > 0; off >>= 1) s += __shfl_down(s, off);
    if ((tid & 63) == 0) rbuf[tid >> 6] = s;
    __syncthreads();
    if (tid == 0)
        atomicAdd(out, 0.5f * ((rbuf[0] + rbuf[1]) + (rbuf[2] + rbuf[3])));
}

extern "C" void kernel_launch(void* const* d_in, const int* in_sizes, int n_in,
                              void* d_out, int out_size, void* d_ws, size_t ws_size,
                              hipStream_t stream) {
    const float* P = (const float*)d_in[0];   // p[0] = first 32*2048*4 floats
    const float* Q = (const float*)d_in[1];
    float* out = (float*)d_out;
    float* ws  = (float*)d_ws;                // needs 16 MiB + 2 KiB

    hipMemsetAsync(out, 0, sizeof(float), stream);
    dim3 g1(NBI, NBATCH);                      // 16 x 32 = 512 blocks, 2/CU
    chamfer_main_kernel<<<g1, 256, 0, stream>>>(P, Q, ws);
    chamfer_finish_kernel<<<256, 256, 0, stream>>>(ws, Q, out);
}